// Round 10
// baseline (302.614 us; speedup 1.0000x reference)
//
#include <hip/hip_runtime.h>
#include <hip/hip_bf16.h>
#include <math.h>

#define B_    8
#define T_    2560
#define F_    229
#define C1_   5
#define C2_   11
#define W1_   114
#define W2_   57
#define KP_   640
#define OF_   88
#define MC_   48
#define G_    8
#define DH_   6
#define K_    31
#define PAD_  15
#define BN_EPS 1e-5f
#define LN_EPS 1e-5f
#define TS_   10    // conv t-tile
#define TT_   16    // attn t-tile

typedef __attribute__((ext_vector_type(8))) short short8;
typedef __attribute__((ext_vector_type(4))) float f32x4;
typedef _Float16 h2 __attribute__((ext_vector_type(2)));
typedef __fp16 fp16x2 __attribute__((ext_vector_type(2)));

static inline int cdiv(int a, int b) { return (a + b - 1) / b; }

union H2U { h2 h; unsigned u; };

__device__ inline h2 uph2(unsigned u) { H2U x; x.u = u; return x.h; }
__device__ inline unsigned packh2(float lo, float hi) {
    H2U x;
    x.h.x = (_Float16)lo;
    x.h.y = (_Float16)hi;
    return x.u;
}

#if __has_builtin(__builtin_amdgcn_cvt_pkrtz)
__device__ inline unsigned pkrtz(float a, float b) {
    union { fp16x2 v; unsigned u; } x;
    x.v = __builtin_amdgcn_cvt_pkrtz(a, b);
    return x.u;
}
#else
__device__ inline unsigned pkrtz(float a, float b) { return packh2(a, b); }
#endif

#if __has_builtin(__builtin_amdgcn_fdot2)
#define FDOT2(a, b, c) __builtin_amdgcn_fdot2((a), (b), (c), false)
#else
__device__ inline float FDOT2(h2 a, h2 b, float c) {
    return fmaf((float)a.x, (float)b.x, fmaf((float)a.y, (float)b.y, c));
}
#endif

// -------- W' = [wq;wk;wv] @ fc_w -> bf16 [144][640] (padded), b' fp32 --------
__global__ __launch_bounds__(256) void wprime_kernel(const float* __restrict__ fc_w,
        const float* __restrict__ fc_b, const float* __restrict__ wq,
        const float* __restrict__ wk, const float* __restrict__ wv,
        __hip_bfloat16* __restrict__ wp, float* __restrict__ bp) {
    int idx = blockIdx.x * 256 + threadIdx.x;
    if (idx < 144 * KP_) {
        int o = idx / KP_;
        int kk = idx % KP_;
        const float* Wrow = (o < 48) ? (wq + o * 88)
                          : (o < 96) ? (wk + (o - 48) * 88) : (wv + (o - 96) * 88);
        float s = 0.f;
        if (kk < 627)
            for (int i = 0; i < 88; ++i) s = fmaf(Wrow[i], fc_w[(size_t)i * 627 + kk], s);
        wp[idx] = __float2bfloat16(s);
    } else if (idx < 144 * KP_ + 144) {
        int o = idx - 144 * KP_;
        const float* Wrow = (o < 48) ? (wq + o * 88)
                          : (o < 96) ? (wk + (o - 48) * 88) : (wv + (o - 96) * 88);
        float s = 0.f;
        for (int i = 0; i < 88; ++i) s = fmaf(Wrow[i], fc_b[i], s);
        bp[o] = s;
    }
}

// ---- fused conv1+conv2+pool+conv3+pool + FC/QKV MFMA: spec -> Q [bt][144] ----
// Phase 3 lands in LDS (x3t, XOR-swizzle byte^=(row&7)<<4 both sides).
// QKV W'-fragments are prefetched 4-deep: first 4 issued BEFORE phase 3 (their
// L2 latency hides under phase-3 conv VALU), then a rolling statically-indexed
// prefetch through the fully-unrolled k-loop. x3 never touches global memory.
__global__ __launch_bounds__(640, 8) void conv123_qkv_kernel(
        const float* __restrict__ spec,
        const float* __restrict__ c1w, const float* __restrict__ c1b,
        const float* __restrict__ g1, const float* __restrict__ b1,
        const float* __restrict__ m1, const float* __restrict__ v1,
        const float* __restrict__ c2w, const float* __restrict__ c2b,
        const float* __restrict__ g2, const float* __restrict__ b2,
        const float* __restrict__ m2, const float* __restrict__ v2,
        const float* __restrict__ c3w, const float* __restrict__ c3b,
        const float* __restrict__ g3, const float* __restrict__ b3,
        const float* __restrict__ m3, const float* __restrict__ v3,
        const __hip_bfloat16* __restrict__ Wp, const float* __restrict__ bp,
        float* __restrict__ Q) {
    __shared__ __align__(16) ushort x1t[70 * 240];    // 33,600 B; reused as x3t[16][640]
    __shared__ __align__(16) ushort x2u[7216];        // 14,432 B: spec tile then x2p
    __shared__ __align__(16) unsigned w1p[60];
    __shared__ __align__(16) unsigned w2p[300];
    __shared__ __align__(16) unsigned w3p[660];
    __shared__ float scl1[5], shf1[5], scl2[5], shf2[5], scl3[11], shf3[11];
    int t0 = blockIdx.x * TS_;
    int b = blockIdx.y;
    int tid = threadIdx.x;

    // ---- weight packing + BN folding ----
    if (tid < 15) {
        int co = tid / 3, dt = tid % 3;
        const float* wpt = c1w + co * 9 + dt * 3;
        unsigned* dst = &w1p[tid * 4];
        dst[0] = packh2(wpt[0], wpt[1]);
        dst[1] = packh2(wpt[2], 0.f);
        dst[2] = packh2(0.f, wpt[0]);
        dst[3] = packh2(wpt[1], wpt[2]);
    }
    for (int i = tid; i < 75; i += 640) {
        int r = i % 15;
        const float* wpt = c2w + (i / 15) * 45 + (r / 3) * 9 + (r % 3) * 3;
        unsigned* dst = &w2p[i * 4];
        dst[0] = packh2(wpt[0], wpt[1]);
        dst[1] = packh2(wpt[2], 0.f);
        dst[2] = packh2(0.f, wpt[0]);
        dst[3] = packh2(wpt[1], wpt[2]);
    }
    for (int i = tid; i < 165; i += 640) {
        int r = i % 15;
        const float* wpt = c3w + (i / 15) * 45 + (r / 3) * 9 + (r % 3) * 3;
        unsigned* dst = &w3p[i * 4];
        dst[0] = packh2(wpt[0], wpt[1]);
        dst[1] = packh2(wpt[2], 0.f);
        dst[2] = packh2(0.f, wpt[0]);
        dst[3] = packh2(wpt[1], wpt[2]);
    }
    if (tid < 5) {
        float s = g1[tid] * rsqrtf(v1[tid] + BN_EPS);
        scl1[tid] = s;
        shf1[tid] = (c1b[tid] - m1[tid]) * s + b1[tid];
    }
    if (tid >= 64 && tid < 69) {
        int c = tid - 64;
        float s = g2[c] * rsqrtf(v2[c] + BN_EPS);
        scl2[c] = s;
        shf2[c] = (c2b[c] - m2[c]) * s + b2[c];
    }
    if (tid >= 128 && tid < 139) {
        int c = tid - 128;
        float s = g3[c] * rsqrtf(v3[c] + BN_EPS);
        scl3[c] = s;
        shf3[c] = (c3b[c] - m3[c]) * s + b3[c];
    }
    // ---- stage spec tile as f16 (rows t0-3..t0+12, pad 4, stride 240) ----
    {
        const float* sb = spec + (size_t)b * T_ * F_;
        for (int i = tid; i < 16 * 120; i += 640) {
            int row = i / 120;
            int pr = i - row * 120;
            int t = t0 - 3 + row;
            int c = 2 * pr - 4;
            float va = 0.f, vb = 0.f;
            if (t >= 0 && t < T_) {
                const float* rp = sb + (size_t)t * F_;
                if ((unsigned)c < 229u) va = rp[c];
                if ((unsigned)(c + 1) < 229u) vb = rp[c + 1];
            }
            *(unsigned*)&x2u[row * 240 + 2 * pr] = packh2(va, vb);
        }
        if (tid == 0) {    // guard region for phase3 edge reads
            uint4 z = {0u, 0u, 0u, 0u};
            *(uint4*)&x2u[7200] = z;
            *(uint4*)&x2u[7208] = z;
        }
    }
    __syncthreads();

    // ---- phase 1: conv1+bn+relu -> x1t rows rr1=0..13 (t = t0-2+rr1) ----
    if (tid < 580) {
        int co = tid / 116;
        int rem = tid - co * 116;
        int q = rem >> 2;
        int rg = rem & 3;
        int rlo = rg * 3 + (rg ? 1 : 0);       // {0,4,7,10}
        const unsigned* wb = &w1p[co * 12];
        uint4 wv0 = *(const uint4*)wb;
        uint4 wv1 = *(const uint4*)(wb + 4);
        uint4 wv2 = *(const uint4*)(wb + 8);
        h2 A1[3] = {uph2(wv0.x), uph2(wv1.x), uph2(wv2.x)};
        h2 B1[3] = {uph2(wv0.y), uph2(wv1.y), uph2(wv2.y)};
        h2 C1v[3] = {uph2(wv0.z), uph2(wv1.z), uph2(wv2.z)};
        h2 D1[3] = {uph2(wv0.w), uph2(wv1.w), uph2(wv2.w)};
        h2 X[6][5];
        const ushort* sp = x2u + 8 * q;
#pragma unroll
        for (int s = 0; s < 6; ++s) {
            const ushort* p = sp + (rlo + s) * 240;
            uint4 xq = *(const uint4*)p;
            unsigned xr = *(const unsigned*)(p + 8);
            X[s][0] = uph2(xq.x); X[s][1] = uph2(xq.y);
            X[s][2] = uph2(xq.z); X[s][3] = uph2(xq.w);
            X[s][4] = uph2(xr);
        }
        float s1 = scl1[co], h1 = shf1[co];
        int c0 = 8 * q - 3;
#pragma unroll
        for (int k = 0; k < 4; ++k) {
            int rr1 = rlo + k;
            int t = t0 - 2 + rr1;
            bool vt = (t >= 0 && t < T_);
            float y[8] = {0.f, 0.f, 0.f, 0.f, 0.f, 0.f, 0.f, 0.f};
#pragma unroll
            for (int dt = 0; dt < 3; ++dt) {
#pragma unroll
                for (int l = 0; l < 4; ++l) {
                    y[2 * l] = FDOT2(X[k + dt][l + 1], B1[dt],
                               FDOT2(X[k + dt][l], A1[dt], y[2 * l]));
                    y[2 * l + 1] = FDOT2(X[k + dt][l + 1], D1[dt],
                                   FDOT2(X[k + dt][l], C1v[dt], y[2 * l + 1]));
                }
            }
            unsigned pk[4];
#pragma unroll
            for (int m = 0; m < 4; ++m) {
                float ya = fmaxf(fmaf(y[2 * m], s1, h1), 0.f);
                float yb = fmaxf(fmaf(y[2 * m + 1], s1, h1), 0.f);
                ya = (vt && (c0 + 2 * m) >= 0) ? ya : 0.f;
                yb = (vt && (c0 + 2 * m + 1) >= 0) ? yb : 0.f;
                pk[m] = pkrtz(ya, yb);
            }
            uint4 pw = {pk[0], pk[1], pk[2], pk[3]};
            *(uint4*)&x1t[(rr1 * 5 + co) * 240 + 8 * q] = pw;
        }
    }
    if (tid < 70) {   // zero tail cols (orig 229..236) so phase2 b128 reads are clean
        uint4 z = {0u, 0u, 0u, 0u};
        *(uint4*)&x1t[tid * 240 + 232] = z;
    }
    __syncthreads();

    // ---- phase 2: conv2+bn+relu+pool_f -> x2p rows r=0..11 (t = t0-1+r) ----
    if (tid < 580) {
        int co2 = tid / 116;
        int rem = tid - co2 * 116;
        int q22 = rem >> 2;
        int rg = rem & 3;
        int rlo2 = rg * 3;                     // {0,3,6,9}
        float aE2[3][4], aO2[3][4];
#pragma unroll
        for (int i = 0; i < 3; ++i)
#pragma unroll
            for (int l = 0; l < 4; ++l) { aE2[i][l] = 0.f; aO2[i][l] = 0.f; }
        const ushort* px = x1t + 8 * q22;
        for (int ci = 0; ci < 5; ++ci) {
            const unsigned* wb = &w2p[(co2 * 5 + ci) * 12];
            uint4 wv0 = *(const uint4*)wb;
            uint4 wv1 = *(const uint4*)(wb + 4);
            uint4 wv2 = *(const uint4*)(wb + 8);
            h2 A[3] = {uph2(wv0.x), uph2(wv1.x), uph2(wv2.x)};
            h2 Bb[3] = {uph2(wv0.y), uph2(wv1.y), uph2(wv2.y)};
            h2 Cc[3] = {uph2(wv0.z), uph2(wv1.z), uph2(wv2.z)};
            h2 Dd[3] = {uph2(wv0.w), uph2(wv1.w), uph2(wv2.w)};
#pragma unroll
            for (int k = 0; k < 5; ++k) {
                const ushort* p = px + ((rlo2 + k) * 5 + ci) * 240;
                uint4 xq = *(const uint4*)p;
                unsigned xr = *(const unsigned*)(p + 8);
                h2 X[5] = {uph2(xq.x), uph2(xq.y), uph2(xq.z), uph2(xq.w), uph2(xr)};
#pragma unroll
                for (int dt = 0; dt < 3; ++dt) {
                    int lr = k - dt;
                    if (lr >= 0 && lr < 3) {
#pragma unroll
                        for (int l = 0; l < 4; ++l) {
                            aE2[lr][l] = FDOT2(X[l + 1], Bb[dt],
                                         FDOT2(X[l], A[dt], aE2[lr][l]));
                            aO2[lr][l] = FDOT2(X[l + 1], Dd[dt],
                                         FDOT2(X[l], Cc[dt], aO2[lr][l]));
                        }
                    }
                }
            }
        }
        float s = scl2[co2], sh = shf2[co2];
#pragma unroll
        for (int lr = 0; lr < 3; ++lr) {
            int r = rlo2 + lr;
            int t = t0 - 1 + r;
            bool vt = (t >= 0 && t < T_);
            float yv[4];
#pragma unroll
            for (int l = 0; l < 4; ++l) {
                int j = 4 * q22 - 1 + l;
                float y = fmaxf(fmaxf(fmaf(aE2[lr][l], s, sh), 0.f),
                                fmaxf(fmaf(aO2[lr][l], s, sh), 0.f));
                yv[l] = (vt && j >= 0 && j < 114) ? y : 0.f;
            }
            uint2 pw;
            pw.x = pkrtz(yv[0], yv[1]);
            pw.y = pkrtz(yv[2], yv[3]);
            *(uint2*)&x2u[(r * 5 + co2) * 120 + 4 * q22] = pw;
        }
    }
    __syncthreads();

    // ---- QKV W' prefetch: issue 4 b-fragments now; latency hides under phase 3 ----
    int w = tid >> 6;
    int lane = tid & 63;
    const short* wrow_q = (const short*)Wp;
    float bias_q = 0.f;
    short8 bv0, bv1, bv2, bv3;
    if (w < 9) {
        int r16 = lane & 15;
        int kq = (lane >> 4) * 8;
        wrow_q = (const short*)Wp + (size_t)(w * 16 + r16) * KP_ + kq;
        bias_q = bp[w * 16 + r16];
        bv0 = *(const short8*)(wrow_q);
        bv1 = *(const short8*)(wrow_q + 32);
        bv2 = *(const short8*)(wrow_q + 64);
        bv3 = *(const short8*)(wrow_q + 96);
    }

    // ---- phase 3: conv3+bn+relu+pool_f -> x3t bf16 (swizzled LDS);
    //      idle threads zero pad rows 10..15 and cols 627..639 of rows 0..9 ----
    ushort* x3t = x1t;
    if (tid < 495) {
        int co = tid / 45;
        int rem = tid - co * 45;
        int pq = rem / 3;
        int rg = rem - pq * 3;
        int rlo = rg * 3;                      // {0,3,6}
        float aE[4][4], aO[4][4];
#pragma unroll
        for (int i = 0; i < 4; ++i)
#pragma unroll
            for (int l = 0; l < 4; ++l) { aE[i][l] = 0.f; aO[i][l] = 0.f; }
        const ushort* px = x2u + 8 * pq;
        for (int ci = 0; ci < 5; ++ci) {
            const unsigned* wb = &w3p[(co * 5 + ci) * 12];
            uint4 wv0 = *(const uint4*)wb;
            uint4 wv1 = *(const uint4*)(wb + 4);
            uint4 wv2 = *(const uint4*)(wb + 8);
            h2 A[3] = {uph2(wv0.x), uph2(wv1.x), uph2(wv2.x)};
            h2 Bb[3] = {uph2(wv0.y), uph2(wv1.y), uph2(wv2.y)};
            h2 Cc[3] = {uph2(wv0.z), uph2(wv1.z), uph2(wv2.z)};
            h2 Dd[3] = {uph2(wv0.w), uph2(wv1.w), uph2(wv2.w)};
#pragma unroll
            for (int k = 0; k < 6; ++k) {
                const ushort* p = px + ((rlo + k) * 5 + ci) * 120;
                uint4 xq = *(const uint4*)p;
                unsigned xr = *(const unsigned*)(p + 8);
                h2 X[5] = {uph2(xq.x), uph2(xq.y), uph2(xq.z), uph2(xq.w), uph2(xr)};
#pragma unroll
                for (int dt = 0; dt < 3; ++dt) {
                    int lr = k - dt;
                    if (lr >= 0 && lr < 4) {
#pragma unroll
                        for (int l = 0; l < 4; ++l) {
                            aE[lr][l] = FDOT2(X[l + 1], Bb[dt],
                                        FDOT2(X[l], A[dt], aE[lr][l]));
                            aO[lr][l] = FDOT2(X[l + 1], Dd[dt],
                                        FDOT2(X[l], Cc[dt], aO[lr][l]));
                        }
                    }
                }
            }
        }
        float s = scl3[co], sh = shf3[co];
#pragma unroll
        for (int lr = 0; lr < 4; ++lr) {
            int r = rlo + lr;                  // 0..9
            int swz = (r & 7) << 4;
            char* rowb = (char*)x3t + r * 1280;
#pragma unroll
            for (int l = 0; l < 4; ++l) {
                int j = 4 * pq + l;
                if (j < 57) {
                    float y = fmaxf(fmaxf(fmaf(aE[lr][l], s, sh), 0.f),
                                    fmaxf(fmaf(aO[lr][l], s, sh), 0.f));
                    __hip_bfloat16 hv = __float2bfloat16(y);
                    int c = co * 57 + j;
                    *(ushort*)(rowb + ((c * 2) ^ swz)) = *(ushort*)&hv;
                }
            }
        }
    } else {
        int idx = tid - 495;                   // 0..144
        uint4 z = {0u, 0u, 0u, 0u};
        for (int i = idx; i < 480; i += 145) { // rows 10..15, full 1280 B each
            int row = 10 + i / 80;
            int c16 = i - (i / 80) * 80;
            *(uint4*)((char*)x3t + row * 1280 + c16 * 16) = z;
        }
        for (int i = idx; i < 130; i += 145) { // rows 0..9, cols 627..639
            int r = i / 13;
            int c = 627 + (i - r * 13);
            int swz = (r & 7) << 4;
            *(ushort*)((char*)x3t + r * 1280 + ((c * 2) ^ swz)) = 0;
        }
    }
    __syncthreads();

    // ---- QKV phase: Q[t0+r][o] = x3t[r] . W'[o] + b'[o], via MFMA ----
    if (w < 9) {
        int r16 = lane & 15;
        int kq = (lane >> 4) * 8;
        const char* x3b = (const char*)x3t + r16 * 1280;
        int swz = (r16 & 7) << 4;
        f32x4 acc = {0.f, 0.f, 0.f, 0.f};
        short8 Bf[20];
        Bf[0] = bv0; Bf[1] = bv1; Bf[2] = bv2; Bf[3] = bv3;
#pragma unroll
        for (int kt = 0; kt < 20; ++kt) {
            if (kt + 4 < 20)
                Bf[kt + 4] = *(const short8*)(wrow_q + (kt + 4) * 32);
            int boff = ((kq + kt * 32) * 2) ^ swz;
            short8 a = *(const short8*)(x3b + boff);
            acc = __builtin_amdgcn_mfma_f32_16x16x32_bf16(a, Bf[kt], acc, 0, 0, 0);
        }
        int o = w * 16 + r16;
        int rg4 = (lane >> 4) * 4;
#pragma unroll
        for (int i = 0; i < 4; ++i) {
            int r = rg4 + i;
            if (r < 10)
                Q[((size_t)b * T_ + t0 + r) * 144 + o] = acc[i] + bias_q;
        }
    }
}

// ----- attention + LN + linear + sigmoid; split-kp via shfl_xor pairs -----
__global__ __launch_bounds__(256) void attn_ln_kernel(const float* __restrict__ Q,
        const float* __restrict__ rel, const float* __restrict__ lng,
        const float* __restrict__ lnb, const float* __restrict__ lw,
        const float* __restrict__ lb, float* __restrict__ fp,
        float* __restrict__ aout) {
    __shared__ float smem[6088];     // kvt[0,4600) relT[4600,6088)
                                     // reuse after drain: abuf[0,3968) xr[3968,4736)
    __shared__ float mus[TT_], rss[TT_];
    float* kvt = smem;               // 46 rows x 100 (k: 0..47, v: 48..95)
    float* relT = smem + 4600;       // [kp][j]
    int b = blockIdx.y;
    int t0 = blockIdx.x * TT_;
    int tid = threadIdx.x;
    int h = tid & 1;                 // tap-parity half
    int p = tid >> 1;                // pair id 0..127
    int g = p & 7;
    int tl = p >> 3;                 // 0..15
    for (int i = tid; i < 46 * 48; i += 256) {
        int row = i / 48, c2 = i % 48;
        int t = t0 - 15 + row;
        float2 v = {0.f, 0.f};
        if (t >= 0 && t < T_)
            v = *(const float2*)&Q[((size_t)b * T_ + t) * 144 + 48 + 2 * c2];
        *(float2*)&kvt[row * 100 + 2 * c2] = v;
    }
    for (int i = tid; i < 31 * 48; i += 256) {
        int kp = i / 48, j = i % 48;
        relT[i] = rel[j * 31 + kp];
    }
    const float* qg = &Q[((size_t)b * T_ + t0 + tl) * 144 + g * 6];
    float2 q01 = *(const float2*)qg;
    float2 q23 = *(const float2*)(qg + 2);
    float2 q45 = *(const float2*)(qg + 4);
    __syncthreads();
    float e[16];
    float m_h = -1e30f;
#pragma unroll
    for (int i = 0; i < 16; ++i) {
        int kp = 2 * i + h;
        if (kp < 31) {
            const float* kr = &kvt[(tl + kp) * 100 + g * 6];
            const float* rr = &relT[kp * 48 + g * 6];
            float2 k01 = *(const float2*)kr;
            float2 k23 = *(const float2*)(kr + 2);
            float2 k45 = *(const float2*)(kr + 4);
            float2 r01 = *(const float2*)rr;
            float2 r23 = *(const float2*)(rr + 2);
            float2 r45 = *(const float2*)(rr + 4);
            float s = fmaf(q01.x, k01.x + r01.x,
                      fmaf(q01.y, k01.y + r01.y,
                      fmaf(q23.x, k23.x + r23.x,
                      fmaf(q23.y, k23.y + r23.y,
                      fmaf(q45.x, k45.x + r45.x,
                           q45.y * (k45.y + r45.y))))));
            e[i] = s;
            m_h = fmaxf(m_h, s);
        }
    }
    float M = fmaxf(m_h, __shfl_xor(m_h, 1));
    float s_h = 0.f;
    float o0 = 0, o1 = 0, o2 = 0, o3 = 0, o4 = 0, o5 = 0;
#pragma unroll
    for (int i = 0; i < 16; ++i) {
        int kp = 2 * i + h;
        if (kp < 31) {
            float a = __expf(e[i] - M);
            e[i] = a;
            s_h += a;
            const float* vr = &kvt[(tl + kp) * 100 + 48 + g * 6];
            float2 v01 = *(const float2*)vr;
            float2 v23 = *(const float2*)(vr + 2);
            float2 v45 = *(const float2*)(vr + 4);
            o0 = fmaf(a, v01.x, o0); o1 = fmaf(a, v01.y, o1);
            o2 = fmaf(a, v23.x, o2); o3 = fmaf(a, v23.y, o3);
            o4 = fmaf(a, v45.x, o4); o5 = fmaf(a, v45.y, o5);
        }
    }
    float sum = s_h + __shfl_xor(s_h, 1);
    float inv = 1.f / sum;
    float t0s = o0 + __shfl_xor(o0, 1);
    float t1s = o1 + __shfl_xor(o1, 1);
    float t2s = o2 + __shfl_xor(o2, 1);
    float t3s = o3 + __shfl_xor(o3, 1);
    float t4s = o4 + __shfl_xor(o4, 1);
    float t5s = o5 + __shfl_xor(o5, 1);
    __syncthreads();                 // all kvt/relT reads complete; reuse LDS
    float* abuf = smem;              // [t][g][31] = 3968 floats
    float* xr = smem + 3968;         // 16 x 48
#pragma unroll
    for (int i = 0; i < 16; ++i) {
        int kp = 2 * i + h;
        if (kp < 31) abuf[p * 31 + kp] = e[i] * inv;
    }
    if (h == 0) {
        float* xp = &xr[tl * 48 + g * 6];
        xp[0] = t0s * inv; xp[1] = t1s * inv; xp[2] = t2s * inv;
        xp[3] = t3s * inv; xp[4] = t4s * inv; xp[5] = t5s * inv;
    }
    __syncthreads();
    size_t base = ((size_t)b * T_ + t0) * 248;
    for (int i = tid; i < 992; i += 256) {
        float4 v = *(const float4*)&abuf[4 * i];
        *(float4*)&aout[base + 4 * i] = v;
    }
    if (tid < 64) {                  // wave-parallel LN stats: 4 lanes per row
        int r = tid >> 2, sub = tid & 3;
        const float* row = &xr[r * 48 + sub * 12];
        float s = 0.f;
#pragma unroll
        for (int c = 0; c < 12; ++c) s += row[c];
        s += __shfl_xor(s, 1);
        s += __shfl_xor(s, 2);
        float mu = s * (1.f / 48.f);
        float v2 = 0.f;
#pragma unroll
        for (int c = 0; c < 12; ++c) { float d = row[c] - mu; v2 = fmaf(d, d, v2); }
        v2 += __shfl_xor(v2, 1);
        v2 += __shfl_xor(v2, 2);
        if (sub == 0) {
            mus[r] = mu;
            rss[r] = rsqrtf(v2 * (1.f / 48.f) + LN_EPS);
        }
    }
    __syncthreads();
    for (int i = tid; i < TT_ * 48; i += 256) {
        int r = i / 48, c = i % 48;
        xr[i] = fmaf((xr[i] - mus[r]) * rss[r], lng[c], lnb[c]);
    }
    __syncthreads();
    size_t obase = ((size_t)b * T_ + t0) * 88;
    for (int i = tid; i < TT_ * 88; i += 256) {
        int o = i % 88, r = i / 88;
        const float* xp = &xr[r * 48];
        const float* wpp = &lw[o * 48];
        float s = lb[o];
#pragma unroll
        for (int c = 0; c < 48; c += 4) {
            float4 xv = *(const float4*)&xp[c];
            float4 wv = *(const float4*)&wpp[c];
            s = fmaf(xv.x, wv.x, s);
            s = fmaf(xv.y, wv.y, s);
            s = fmaf(xv.z, wv.z, s);
            s = fmaf(xv.w, wv.w, s);
        }
        fp[obase + i] = 1.f / (1.f + __expf(-s));
    }
}

extern "C" void kernel_launch(void* const* d_in, const int* in_sizes, int n_in,
                              void* d_out, int out_size, void* d_ws, size_t ws_size,
                              hipStream_t stream) {
    const float* spec = (const float*)d_in[0];
    const float* c1_w = (const float*)d_in[1];
    const float* c1_b = (const float*)d_in[2];
    const float* bn1_g = (const float*)d_in[3];
    const float* bn1_b = (const float*)d_in[4];
    const float* bn1_m = (const float*)d_in[5];
    const float* bn1_v = (const float*)d_in[6];
    const float* c2_w = (const float*)d_in[7];
    const float* c2_b = (const float*)d_in[8];
    const float* bn2_g = (const float*)d_in[9];
    const float* bn2_b = (const float*)d_in[10];
    const float* bn2_m = (const float*)d_in[11];
    const float* bn2_v = (const float*)d_in[12];
    const float* c3_w = (const float*)d_in[13];
    const float* c3_b = (const float*)d_in[14];
    const float* bn3_g = (const float*)d_in[15];
    const float* bn3_b = (const float*)d_in[16];
    const float* bn3_m = (const float*)d_in[17];
    const float* bn3_v = (const float*)d_in[18];
    const float* fc_w = (const float*)d_in[19];
    const float* fc_b = (const float*)d_in[20];
    const float* wq = (const float*)d_in[21];
    const float* wk = (const float*)d_in[22];
    const float* wv = (const float*)d_in[23];
    const float* rel = (const float*)d_in[24];
    const float* ln_g = (const float*)d_in[25];
    const float* ln_b = (const float*)d_in[26];
    const float* lin_w = (const float*)d_in[27];
    const float* lin_b = (const float*)d_in[28];

    float* ws = (float*)d_ws;
    __hip_bfloat16* wp_bf = (__hip_bfloat16*)(ws + 19000000);
    float* bp = ws + 19100000;
    float* Qb = ws + 23449600;

    float* frame_pred = (float*)d_out;
    float* a_out = frame_pred + (size_t)B_ * T_ * OF_;

    wprime_kernel<<<cdiv(144 * KP_ + 144, 256), 256, 0, stream>>>(fc_w, fc_b, wq, wk, wv,
                                                                  wp_bf, bp);
    conv123_qkv_kernel<<<dim3(T_ / TS_, B_), 640, 0, stream>>>(
        spec, c1_w, c1_b, bn1_g, bn1_b, bn1_m, bn1_v,
        c2_w, c2_b, bn2_g, bn2_b, bn2_m, bn2_v,
        c3_w, c3_b, bn3_g, bn3_b, bn3_m, bn3_v, wp_bf, bp, Qb);
    attn_ln_kernel<<<dim3(T_ / TT_, B_), 256, 0, stream>>>(Qb, rel, ln_g, ln_b, lin_w,
                                                           lin_b, frame_pred, a_out);
}

// Round 11
// 283.645 us; speedup vs baseline: 1.0669x; 1.0669x over previous
//
#include <hip/hip_runtime.h>
#include <hip/hip_bf16.h>
#include <math.h>

#define B_    8
#define T_    2560
#define F_    229
#define C1_   5
#define C2_   11
#define W1_   114
#define W2_   57
#define KP_   640
#define OF_   88
#define MC_   48
#define G_    8
#define DH_   6
#define K_    31
#define PAD_  15
#define BN_EPS 1e-5f
#define LN_EPS 1e-5f
#define TS_   10    // conv t-tile
#define TT_   16    // attn t-tile

typedef __attribute__((ext_vector_type(8))) short short8;
typedef __attribute__((ext_vector_type(4))) float f32x4;
typedef _Float16 h2 __attribute__((ext_vector_type(2)));
typedef __fp16 fp16x2 __attribute__((ext_vector_type(2)));

static inline int cdiv(int a, int b) { return (a + b - 1) / b; }

union H2U { h2 h; unsigned u; };

__device__ inline h2 uph2(unsigned u) { H2U x; x.u = u; return x.h; }
__device__ inline unsigned packh2(float lo, float hi) {
    H2U x;
    x.h.x = (_Float16)lo;
    x.h.y = (_Float16)hi;
    return x.u;
}

#if __has_builtin(__builtin_amdgcn_cvt_pkrtz)
__device__ inline unsigned pkrtz(float a, float b) {
    union { fp16x2 v; unsigned u; } x;
    x.v = __builtin_amdgcn_cvt_pkrtz(a, b);
    return x.u;
}
#else
__device__ inline unsigned pkrtz(float a, float b) { return packh2(a, b); }
#endif

#if __has_builtin(__builtin_amdgcn_fdot2)
#define FDOT2(a, b, c) __builtin_amdgcn_fdot2((a), (b), (c), false)
#else
__device__ inline float FDOT2(h2 a, h2 b, float c) {
    return fmaf((float)a.x, (float)b.x, fmaf((float)a.y, (float)b.y, c));
}
#endif

// -------- W' = [wq;wk;wv] @ fc_w -> bf16 [144][640] (padded), b' fp32 --------
__global__ __launch_bounds__(256) void wprime_kernel(const float* __restrict__ fc_w,
        const float* __restrict__ fc_b, const float* __restrict__ wq,
        const float* __restrict__ wk, const float* __restrict__ wv,
        __hip_bfloat16* __restrict__ wp, float* __restrict__ bp) {
    int idx = blockIdx.x * 256 + threadIdx.x;
    if (idx < 144 * KP_) {
        int o = idx / KP_;
        int kk = idx % KP_;
        const float* Wrow = (o < 48) ? (wq + o * 88)
                          : (o < 96) ? (wk + (o - 48) * 88) : (wv + (o - 96) * 88);
        float s = 0.f;
        if (kk < 627)
            for (int i = 0; i < 88; ++i) s = fmaf(Wrow[i], fc_w[(size_t)i * 627 + kk], s);
        wp[idx] = __float2bfloat16(s);
    } else if (idx < 144 * KP_ + 144) {
        int o = idx - 144 * KP_;
        const float* Wrow = (o < 48) ? (wq + o * 88)
                          : (o < 96) ? (wk + (o - 48) * 88) : (wv + (o - 96) * 88);
        float s = 0.f;
        for (int i = 0; i < 88; ++i) s = fmaf(Wrow[i], fc_b[i], s);
        bp[o] = s;
    }
}

// ---- fused conv1+conv2+pool+conv3+pool + FC/QKV MFMA: spec -> Q [bt][144] ----
// Phase 3 lands in LDS (x3t, XOR-swizzle byte^=(row&7)<<4 both sides); pad
// zeroing folded into phase-3 idle threads; 9 waves then do QKV = x3 @ W'^T
// + b' via MFMA (in-loop W' loads -- W' is L2-hot; BW-bound not latency-bound;
// DO NOT prefetch into registers: launch_bounds(640,8) caps VGPR at 64 and a
// 20-deep fragment array spills to scratch, +100 MB HBM traffic -- round 10).
__global__ __launch_bounds__(640, 8) void conv123_qkv_kernel(
        const float* __restrict__ spec,
        const float* __restrict__ c1w, const float* __restrict__ c1b,
        const float* __restrict__ g1, const float* __restrict__ b1,
        const float* __restrict__ m1, const float* __restrict__ v1,
        const float* __restrict__ c2w, const float* __restrict__ c2b,
        const float* __restrict__ g2, const float* __restrict__ b2,
        const float* __restrict__ m2, const float* __restrict__ v2,
        const float* __restrict__ c3w, const float* __restrict__ c3b,
        const float* __restrict__ g3, const float* __restrict__ b3,
        const float* __restrict__ m3, const float* __restrict__ v3,
        const __hip_bfloat16* __restrict__ Wp, const float* __restrict__ bp,
        float* __restrict__ Q) {
    __shared__ __align__(16) ushort x1t[70 * 240];    // 33,600 B; reused as x3t[16][640]
    __shared__ __align__(16) ushort x2u[7216];        // 14,432 B: spec tile then x2p
    __shared__ __align__(16) unsigned w1p[60];
    __shared__ __align__(16) unsigned w2p[300];
    __shared__ __align__(16) unsigned w3p[660];
    __shared__ float scl1[5], shf1[5], scl2[5], shf2[5], scl3[11], shf3[11];
    int t0 = blockIdx.x * TS_;
    int b = blockIdx.y;
    int tid = threadIdx.x;

    // ---- weight packing + BN folding ----
    if (tid < 15) {
        int co = tid / 3, dt = tid % 3;
        const float* wpt = c1w + co * 9 + dt * 3;
        unsigned* dst = &w1p[tid * 4];
        dst[0] = packh2(wpt[0], wpt[1]);
        dst[1] = packh2(wpt[2], 0.f);
        dst[2] = packh2(0.f, wpt[0]);
        dst[3] = packh2(wpt[1], wpt[2]);
    }
    for (int i = tid; i < 75; i += 640) {
        int r = i % 15;
        const float* wpt = c2w + (i / 15) * 45 + (r / 3) * 9 + (r % 3) * 3;
        unsigned* dst = &w2p[i * 4];
        dst[0] = packh2(wpt[0], wpt[1]);
        dst[1] = packh2(wpt[2], 0.f);
        dst[2] = packh2(0.f, wpt[0]);
        dst[3] = packh2(wpt[1], wpt[2]);
    }
    for (int i = tid; i < 165; i += 640) {
        int r = i % 15;
        const float* wpt = c3w + (i / 15) * 45 + (r / 3) * 9 + (r % 3) * 3;
        unsigned* dst = &w3p[i * 4];
        dst[0] = packh2(wpt[0], wpt[1]);
        dst[1] = packh2(wpt[2], 0.f);
        dst[2] = packh2(0.f, wpt[0]);
        dst[3] = packh2(wpt[1], wpt[2]);
    }
    if (tid < 5) {
        float s = g1[tid] * rsqrtf(v1[tid] + BN_EPS);
        scl1[tid] = s;
        shf1[tid] = (c1b[tid] - m1[tid]) * s + b1[tid];
    }
    if (tid >= 64 && tid < 69) {
        int c = tid - 64;
        float s = g2[c] * rsqrtf(v2[c] + BN_EPS);
        scl2[c] = s;
        shf2[c] = (c2b[c] - m2[c]) * s + b2[c];
    }
    if (tid >= 128 && tid < 139) {
        int c = tid - 128;
        float s = g3[c] * rsqrtf(v3[c] + BN_EPS);
        scl3[c] = s;
        shf3[c] = (c3b[c] - m3[c]) * s + b3[c];
    }
    // ---- stage spec tile as f16 (rows t0-3..t0+12, pad 4, stride 240) ----
    {
        const float* sb = spec + (size_t)b * T_ * F_;
        for (int i = tid; i < 16 * 120; i += 640) {
            int row = i / 120;
            int pr = i - row * 120;
            int t = t0 - 3 + row;
            int c = 2 * pr - 4;
            float va = 0.f, vb = 0.f;
            if (t >= 0 && t < T_) {
                const float* rp = sb + (size_t)t * F_;
                if ((unsigned)c < 229u) va = rp[c];
                if ((unsigned)(c + 1) < 229u) vb = rp[c + 1];
            }
            *(unsigned*)&x2u[row * 240 + 2 * pr] = packh2(va, vb);
        }
        if (tid == 0) {    // guard region for phase3 edge reads
            uint4 z = {0u, 0u, 0u, 0u};
            *(uint4*)&x2u[7200] = z;
            *(uint4*)&x2u[7208] = z;
        }
    }
    __syncthreads();

    // ---- phase 1: conv1+bn+relu -> x1t rows rr1=0..13 (t = t0-2+rr1) ----
    if (tid < 580) {
        int co = tid / 116;
        int rem = tid - co * 116;
        int q = rem >> 2;
        int rg = rem & 3;
        int rlo = rg * 3 + (rg ? 1 : 0);       // {0,4,7,10}
        const unsigned* wb = &w1p[co * 12];
        uint4 wv0 = *(const uint4*)wb;
        uint4 wv1 = *(const uint4*)(wb + 4);
        uint4 wv2 = *(const uint4*)(wb + 8);
        h2 A1[3] = {uph2(wv0.x), uph2(wv1.x), uph2(wv2.x)};
        h2 B1[3] = {uph2(wv0.y), uph2(wv1.y), uph2(wv2.y)};
        h2 C1v[3] = {uph2(wv0.z), uph2(wv1.z), uph2(wv2.z)};
        h2 D1[3] = {uph2(wv0.w), uph2(wv1.w), uph2(wv2.w)};
        h2 X[6][5];
        const ushort* sp = x2u + 8 * q;
#pragma unroll
        for (int s = 0; s < 6; ++s) {
            const ushort* p = sp + (rlo + s) * 240;
            uint4 xq = *(const uint4*)p;
            unsigned xr = *(const unsigned*)(p + 8);
            X[s][0] = uph2(xq.x); X[s][1] = uph2(xq.y);
            X[s][2] = uph2(xq.z); X[s][3] = uph2(xq.w);
            X[s][4] = uph2(xr);
        }
        float s1 = scl1[co], h1 = shf1[co];
        int c0 = 8 * q - 3;
#pragma unroll
        for (int k = 0; k < 4; ++k) {
            int rr1 = rlo + k;
            int t = t0 - 2 + rr1;
            bool vt = (t >= 0 && t < T_);
            float y[8] = {0.f, 0.f, 0.f, 0.f, 0.f, 0.f, 0.f, 0.f};
#pragma unroll
            for (int dt = 0; dt < 3; ++dt) {
#pragma unroll
                for (int l = 0; l < 4; ++l) {
                    y[2 * l] = FDOT2(X[k + dt][l + 1], B1[dt],
                               FDOT2(X[k + dt][l], A1[dt], y[2 * l]));
                    y[2 * l + 1] = FDOT2(X[k + dt][l + 1], D1[dt],
                                   FDOT2(X[k + dt][l], C1v[dt], y[2 * l + 1]));
                }
            }
            unsigned pk[4];
#pragma unroll
            for (int m = 0; m < 4; ++m) {
                float ya = fmaxf(fmaf(y[2 * m], s1, h1), 0.f);
                float yb = fmaxf(fmaf(y[2 * m + 1], s1, h1), 0.f);
                ya = (vt && (c0 + 2 * m) >= 0) ? ya : 0.f;
                yb = (vt && (c0 + 2 * m + 1) >= 0) ? yb : 0.f;
                pk[m] = pkrtz(ya, yb);
            }
            uint4 pw = {pk[0], pk[1], pk[2], pk[3]};
            *(uint4*)&x1t[(rr1 * 5 + co) * 240 + 8 * q] = pw;
        }
    }
    if (tid < 70) {   // zero tail cols (orig 229..236) so phase2 b128 reads are clean
        uint4 z = {0u, 0u, 0u, 0u};
        *(uint4*)&x1t[tid * 240 + 232] = z;
    }
    __syncthreads();

    // ---- phase 2: conv2+bn+relu+pool_f -> x2p rows r=0..11 (t = t0-1+r) ----
    if (tid < 580) {
        int co2 = tid / 116;
        int rem = tid - co2 * 116;
        int q22 = rem >> 2;
        int rg = rem & 3;
        int rlo2 = rg * 3;                     // {0,3,6,9}
        float aE2[3][4], aO2[3][4];
#pragma unroll
        for (int i = 0; i < 3; ++i)
#pragma unroll
            for (int l = 0; l < 4; ++l) { aE2[i][l] = 0.f; aO2[i][l] = 0.f; }
        const ushort* px = x1t + 8 * q22;
        for (int ci = 0; ci < 5; ++ci) {
            const unsigned* wb = &w2p[(co2 * 5 + ci) * 12];
            uint4 wv0 = *(const uint4*)wb;
            uint4 wv1 = *(const uint4*)(wb + 4);
            uint4 wv2 = *(const uint4*)(wb + 8);
            h2 A[3] = {uph2(wv0.x), uph2(wv1.x), uph2(wv2.x)};
            h2 Bb[3] = {uph2(wv0.y), uph2(wv1.y), uph2(wv2.y)};
            h2 Cc[3] = {uph2(wv0.z), uph2(wv1.z), uph2(wv2.z)};
            h2 Dd[3] = {uph2(wv0.w), uph2(wv1.w), uph2(wv2.w)};
#pragma unroll
            for (int k = 0; k < 5; ++k) {
                const ushort* p = px + ((rlo2 + k) * 5 + ci) * 240;
                uint4 xq = *(const uint4*)p;
                unsigned xr = *(const unsigned*)(p + 8);
                h2 X[5] = {uph2(xq.x), uph2(xq.y), uph2(xq.z), uph2(xq.w), uph2(xr)};
#pragma unroll
                for (int dt = 0; dt < 3; ++dt) {
                    int lr = k - dt;
                    if (lr >= 0 && lr < 3) {
#pragma unroll
                        for (int l = 0; l < 4; ++l) {
                            aE2[lr][l] = FDOT2(X[l + 1], Bb[dt],
                                         FDOT2(X[l], A[dt], aE2[lr][l]));
                            aO2[lr][l] = FDOT2(X[l + 1], Dd[dt],
                                         FDOT2(X[l], Cc[dt], aO2[lr][l]));
                        }
                    }
                }
            }
        }
        float s = scl2[co2], sh = shf2[co2];
#pragma unroll
        for (int lr = 0; lr < 3; ++lr) {
            int r = rlo2 + lr;
            int t = t0 - 1 + r;
            bool vt = (t >= 0 && t < T_);
            float yv[4];
#pragma unroll
            for (int l = 0; l < 4; ++l) {
                int j = 4 * q22 - 1 + l;
                float y = fmaxf(fmaxf(fmaf(aE2[lr][l], s, sh), 0.f),
                                fmaxf(fmaf(aO2[lr][l], s, sh), 0.f));
                yv[l] = (vt && j >= 0 && j < 114) ? y : 0.f;
            }
            uint2 pw;
            pw.x = pkrtz(yv[0], yv[1]);
            pw.y = pkrtz(yv[2], yv[3]);
            *(uint2*)&x2u[(r * 5 + co2) * 120 + 4 * q22] = pw;
        }
    }
    __syncthreads();

    // ---- phase 3: conv3+bn+relu+pool_f -> x3t bf16 (swizzled LDS);
    //      idle threads zero pad rows 10..15 and cols 627..639 of rows 0..9 ----
    ushort* x3t = x1t;
    if (tid < 495) {
        int co = tid / 45;
        int rem = tid - co * 45;
        int pq = rem / 3;
        int rg = rem - pq * 3;
        int rlo = rg * 3;                      // {0,3,6}
        float aE[4][4], aO[4][4];
#pragma unroll
        for (int i = 0; i < 4; ++i)
#pragma unroll
            for (int l = 0; l < 4; ++l) { aE[i][l] = 0.f; aO[i][l] = 0.f; }
        const ushort* px = x2u + 8 * pq;
        for (int ci = 0; ci < 5; ++ci) {
            const unsigned* wb = &w3p[(co * 5 + ci) * 12];
            uint4 wv0 = *(const uint4*)wb;
            uint4 wv1 = *(const uint4*)(wb + 4);
            uint4 wv2 = *(const uint4*)(wb + 8);
            h2 A[3] = {uph2(wv0.x), uph2(wv1.x), uph2(wv2.x)};
            h2 Bb[3] = {uph2(wv0.y), uph2(wv1.y), uph2(wv2.y)};
            h2 Cc[3] = {uph2(wv0.z), uph2(wv1.z), uph2(wv2.z)};
            h2 Dd[3] = {uph2(wv0.w), uph2(wv1.w), uph2(wv2.w)};
#pragma unroll
            for (int k = 0; k < 6; ++k) {
                const ushort* p = px + ((rlo + k) * 5 + ci) * 120;
                uint4 xq = *(const uint4*)p;
                unsigned xr = *(const unsigned*)(p + 8);
                h2 X[5] = {uph2(xq.x), uph2(xq.y), uph2(xq.z), uph2(xq.w), uph2(xr)};
#pragma unroll
                for (int dt = 0; dt < 3; ++dt) {
                    int lr = k - dt;
                    if (lr >= 0 && lr < 4) {
#pragma unroll
                        for (int l = 0; l < 4; ++l) {
                            aE[lr][l] = FDOT2(X[l + 1], Bb[dt],
                                        FDOT2(X[l], A[dt], aE[lr][l]));
                            aO[lr][l] = FDOT2(X[l + 1], Dd[dt],
                                        FDOT2(X[l], Cc[dt], aO[lr][l]));
                        }
                    }
                }
            }
        }
        float s = scl3[co], sh = shf3[co];
#pragma unroll
        for (int lr = 0; lr < 4; ++lr) {
            int r = rlo + lr;                  // 0..9
            int swz = (r & 7) << 4;
            char* rowb = (char*)x3t + r * 1280;
#pragma unroll
            for (int l = 0; l < 4; ++l) {
                int j = 4 * pq + l;
                if (j < 57) {
                    float y = fmaxf(fmaxf(fmaf(aE[lr][l], s, sh), 0.f),
                                    fmaxf(fmaf(aO[lr][l], s, sh), 0.f));
                    __hip_bfloat16 hv = __float2bfloat16(y);
                    int c = co * 57 + j;
                    *(ushort*)(rowb + ((c * 2) ^ swz)) = *(ushort*)&hv;
                }
            }
        }
    } else {
        int idx = tid - 495;                   // 0..144
        uint4 z = {0u, 0u, 0u, 0u};
        for (int i = idx; i < 480; i += 145) { // rows 10..15, full 1280 B each
            int row = 10 + i / 80;
            int c16 = i - (i / 80) * 80;
            *(uint4*)((char*)x3t + row * 1280 + c16 * 16) = z;
        }
        for (int i = idx; i < 130; i += 145) { // rows 0..9, cols 627..639
            int r = i / 13;
            int c = 627 + (i - r * 13);
            int swz = (r & 7) << 4;
            *(ushort*)((char*)x3t + r * 1280 + ((c * 2) ^ swz)) = 0;
        }
    }
    __syncthreads();

    // ---- QKV phase: Q[t0+r][o] = x3t[r] . W'[o] + b'[o], via MFMA ----
    int w = tid >> 6;
    if (w < 9) {
        int lane = tid & 63;
        int r16 = lane & 15;
        int kq = (lane >> 4) * 8;
        const short* Ws = (const short*)Wp;
        const short* wrow = Ws + (size_t)(w * 16 + r16) * KP_ + kq;
        const char* x3b = (const char*)x3t + r16 * 1280;
        int swz = (r16 & 7) << 4;
        f32x4 acc = {0.f, 0.f, 0.f, 0.f};
#pragma unroll 4
        for (int kt = 0; kt < 20; ++kt) {
            int boff = ((kq + kt * 32) * 2) ^ swz;
            short8 a = *(const short8*)(x3b + boff);
            short8 bv = *(const short8*)(wrow + kt * 32);
            acc = __builtin_amdgcn_mfma_f32_16x16x32_bf16(a, bv, acc, 0, 0, 0);
        }
        int o = w * 16 + r16;
        float bias = bp[o];
        int rg4 = (lane >> 4) * 4;
#pragma unroll
        for (int i = 0; i < 4; ++i) {
            int r = rg4 + i;
            if (r < 10)
                Q[((size_t)b * T_ + t0 + r) * 144 + o] = acc[i] + bias;
        }
    }
}

// ----- attention + LN + linear + sigmoid; split-kp via shfl_xor pairs -----
__global__ __launch_bounds__(256) void attn_ln_kernel(const float* __restrict__ Q,
        const float* __restrict__ rel, const float* __restrict__ lng,
        const float* __restrict__ lnb, const float* __restrict__ lw,
        const float* __restrict__ lb, float* __restrict__ fp,
        float* __restrict__ aout) {
    __shared__ float smem[6088];     // kvt[0,4600) relT[4600,6088)
                                     // reuse after drain: abuf[0,3968) xr[3968,4736)
    __shared__ float mus[TT_], rss[TT_];
    float* kvt = smem;               // 46 rows x 100 (k: 0..47, v: 48..95)
    float* relT = smem + 4600;       // [kp][j]
    int b = blockIdx.y;
    int t0 = blockIdx.x * TT_;
    int tid = threadIdx.x;
    int h = tid & 1;                 // tap-parity half
    int p = tid >> 1;                // pair id 0..127
    int g = p & 7;
    int tl = p >> 3;                 // 0..15
    for (int i = tid; i < 46 * 48; i += 256) {
        int row = i / 48, c2 = i % 48;
        int t = t0 - 15 + row;
        float2 v = {0.f, 0.f};
        if (t >= 0 && t < T_)
            v = *(const float2*)&Q[((size_t)b * T_ + t) * 144 + 48 + 2 * c2];
        *(float2*)&kvt[row * 100 + 2 * c2] = v;
    }
    for (int i = tid; i < 31 * 48; i += 256) {
        int kp = i / 48, j = i % 48;
        relT[i] = rel[j * 31 + kp];
    }
    const float* qg = &Q[((size_t)b * T_ + t0 + tl) * 144 + g * 6];
    float2 q01 = *(const float2*)qg;
    float2 q23 = *(const float2*)(qg + 2);
    float2 q45 = *(const float2*)(qg + 4);
    __syncthreads();
    float e[16];
    float m_h = -1e30f;
#pragma unroll
    for (int i = 0; i < 16; ++i) {
        int kp = 2 * i + h;
        if (kp < 31) {
            const float* kr = &kvt[(tl + kp) * 100 + g * 6];
            const float* rr = &relT[kp * 48 + g * 6];
            float2 k01 = *(const float2*)kr;
            float2 k23 = *(const float2*)(kr + 2);
            float2 k45 = *(const float2*)(kr + 4);
            float2 r01 = *(const float2*)rr;
            float2 r23 = *(const float2*)(rr + 2);
            float2 r45 = *(const float2*)(rr + 4);
            float s = fmaf(q01.x, k01.x + r01.x,
                      fmaf(q01.y, k01.y + r01.y,
                      fmaf(q23.x, k23.x + r23.x,
                      fmaf(q23.y, k23.y + r23.y,
                      fmaf(q45.x, k45.x + r45.x,
                           q45.y * (k45.y + r45.y))))));
            e[i] = s;
            m_h = fmaxf(m_h, s);
        }
    }
    float M = fmaxf(m_h, __shfl_xor(m_h, 1));
    float s_h = 0.f;
    float o0 = 0, o1 = 0, o2 = 0, o3 = 0, o4 = 0, o5 = 0;
#pragma unroll
    for (int i = 0; i < 16; ++i) {
        int kp = 2 * i + h;
        if (kp < 31) {
            float a = __expf(e[i] - M);
            e[i] = a;
            s_h += a;
            const float* vr = &kvt[(tl + kp) * 100 + 48 + g * 6];
            float2 v01 = *(const float2*)vr;
            float2 v23 = *(const float2*)(vr + 2);
            float2 v45 = *(const float2*)(vr + 4);
            o0 = fmaf(a, v01.x, o0); o1 = fmaf(a, v01.y, o1);
            o2 = fmaf(a, v23.x, o2); o3 = fmaf(a, v23.y, o3);
            o4 = fmaf(a, v45.x, o4); o5 = fmaf(a, v45.y, o5);
        }
    }
    float sum = s_h + __shfl_xor(s_h, 1);
    float inv = 1.f / sum;
    float t0s = o0 + __shfl_xor(o0, 1);
    float t1s = o1 + __shfl_xor(o1, 1);
    float t2s = o2 + __shfl_xor(o2, 1);
    float t3s = o3 + __shfl_xor(o3, 1);
    float t4s = o4 + __shfl_xor(o4, 1);
    float t5s = o5 + __shfl_xor(o5, 1);
    __syncthreads();                 // all kvt/relT reads complete; reuse LDS
    float* abuf = smem;              // [t][g][31] = 3968 floats
    float* xr = smem + 3968;         // 16 x 48
#pragma unroll
    for (int i = 0; i < 16; ++i) {
        int kp = 2 * i + h;
        if (kp < 31) abuf[p * 31 + kp] = e[i] * inv;
    }
    if (h == 0) {
        float* xp = &xr[tl * 48 + g * 6];
        xp[0] = t0s * inv; xp[1] = t1s * inv; xp[2] = t2s * inv;
        xp[3] = t3s * inv; xp[4] = t4s * inv; xp[5] = t5s * inv;
    }
    __syncthreads();
    size_t base = ((size_t)b * T_ + t0) * 248;
    for (int i = tid; i < 992; i += 256) {
        float4 v = *(const float4*)&abuf[4 * i];
        *(float4*)&aout[base + 4 * i] = v;
    }
    if (tid < 64) {                  // wave-parallel LN stats: 4 lanes per row
        int r = tid >> 2, sub = tid & 3;
        const float* row = &xr[r * 48 + sub * 12];
        float s = 0.f;
#pragma unroll
        for (int c = 0; c < 12; ++c) s += row[c];
        s += __shfl_xor(s, 1);
        s += __shfl_xor(s, 2);
        float mu = s * (1.f / 48.f);
        float v2 = 0.f;
#pragma unroll
        for (int c = 0; c < 12; ++c) { float d = row[c] - mu; v2 = fmaf(d, d, v2); }
        v2 += __shfl_xor(v2, 1);
        v2 += __shfl_xor(v2, 2);
        if (sub == 0) {
            mus[r] = mu;
            rss[r] = rsqrtf(v2 * (1.f / 48.f) + LN_EPS);
        }
    }
    __syncthreads();
    for (int i = tid; i < TT_ * 48; i += 256) {
        int r = i / 48, c = i % 48;
        xr[i] = fmaf((xr[i] - mus[r]) * rss[r], lng[c], lnb[c]);
    }
    __syncthreads();
    size_t obase = ((size_t)b * T_ + t0) * 88;
    for (int i = tid; i < TT_ * 88; i += 256) {
        int o = i % 88, r = i / 88;
        const float* xp = &xr[r * 48];
        const float* wpp = &lw[o * 48];
        float s = lb[o];
#pragma unroll
        for (int c = 0; c < 48; c += 4) {
            float4 xv = *(const float4*)&xp[c];
            float4 wv = *(const float4*)&wpp[c];
            s = fmaf(xv.x, wv.x, s);
            s = fmaf(xv.y, wv.y, s);
            s = fmaf(xv.z, wv.z, s);
            s = fmaf(xv.w, wv.w, s);
        }
        fp[obase + i] = 1.f / (1.f + __expf(-s));
    }
}

extern "C" void kernel_launch(void* const* d_in, const int* in_sizes, int n_in,
                              void* d_out, int out_size, void* d_ws, size_t ws_size,
                              hipStream_t stream) {
    const float* spec = (const float*)d_in[0];
    const float* c1_w = (const float*)d_in[1];
    const float* c1_b = (const float*)d_in[2];
    const float* bn1_g = (const float*)d_in[3];
    const float* bn1_b = (const float*)d_in[4];
    const float* bn1_m = (const float*)d_in[5];
    const float* bn1_v = (const float*)d_in[6];
    const float* c2_w = (const float*)d_in[7];
    const float* c2_b = (const float*)d_in[8];
    const float* bn2_g = (const float*)d_in[9];
    const float* bn2_b = (const float*)d_in[10];
    const float* bn2_m = (const float*)d_in[11];
    const float* bn2_v = (const float*)d_in[12];
    const float* c3_w = (const float*)d_in[13];
    const float* c3_b = (const float*)d_in[14];
    const float* bn3_g = (const float*)d_in[15];
    const float* bn3_b = (const float*)d_in[16];
    const float* bn3_m = (const float*)d_in[17];
    const float* bn3_v = (const float*)d_in[18];
    const float* fc_w = (const float*)d_in[19];
    const float* fc_b = (const float*)d_in[20];
    const float* wq = (const float*)d_in[21];
    const float* wk = (const float*)d_in[22];
    const float* wv = (const float*)d_in[23];
    const float* rel = (const float*)d_in[24];
    const float* ln_g = (const float*)d_in[25];
    const float* ln_b = (const float*)d_in[26];
    const float* lin_w = (const float*)d_in[27];
    const float* lin_b = (const float*)d_in[28];

    float* ws = (float*)d_ws;
    __hip_bfloat16* wp_bf = (__hip_bfloat16*)(ws + 19000000);
    float* bp = ws + 19100000;
    float* Qb = ws + 23449600;

    float* frame_pred = (float*)d_out;
    float* a_out = frame_pred + (size_t)B_ * T_ * OF_;

    wprime_kernel<<<cdiv(144 * KP_ + 144, 256), 256, 0, stream>>>(fc_w, fc_b, wq, wk, wv,
                                                                  wp_bf, bp);
    conv123_qkv_kernel<<<dim3(T_ / TS_, B_), 640, 0, stream>>>(
        spec, c1_w, c1_b, bn1_g, bn1_b, bn1_m, bn1_v,
        c2_w, c2_b, bn2_g, bn2_b, bn2_m, bn2_v,
        c3_w, c3_b, bn3_g, bn3_b, bn3_m, bn3_v, wp_bf, bp, Qb);
    attn_ln_kernel<<<dim3(T_ / TT_, B_), 256, 0, stream>>>(Qb, rel, ln_g, ln_b, lin_w,
                                                           lin_b, frame_pred, a_out);
}